// Round 20
// baseline (170.734 us; speedup 1.0000x reference)
//
#include <hip/hip_runtime.h>
#include <math.h>

// NeuralSplineCoupling: y[:, :3] = RQS(x[:, :3]; params = MLP([x[:,3:], c]))
//                       y[:, 3:] = x[:, 3:],  log_det = sum over 3 dims
// N = 500000, X_DIM=6, C_DIM=4, HID=128, KNOTS=16, SPLINE_DIM=47, OUT_DIM=141
//
// Round 32 == Round 29 resubmit (GPU acquisition timed out 3x; unmeasured).
// r26 (MEASURED 60.8-62.1us main: frag-sharing 2 sets/wave, full
// blob<->shp16 overlay, padded p-layout, deferred-norm scan) + NT=768 HYBRID:
// phase-4 had 12 spline groups over 8 waves -> waves 0-3 ran TWO serial
// bodies (~32 exp + scan + 2 softplus + 2 log each) while 4-7 waited at
// barrier C — the phase-4 wall time was 2 bodies. Now 4 extra waves idle
// through the MLP (waves 8-11) and join at phase 4: 12 groups / 12 waves,
// ONE body per wave. Critical path halves; occupancy 16 -> 24 waves/CU
// (launch_bounds(768,6), VGPR cap ~85, measured 60). LDS unchanged 77824
// -> still 2 blocks/CU. Staging: 7 rounds of 768.
// LDS: blob [0,77824) overlaid by shp16[256][SRS] after BARRIER A.

#define TILE 256
#define NT   768
#define HID  128
#define OUTD 141
#define SRS  152     // halves per sample (304 B rows): 3*48 params + 2 ld-pad
#define BND  5.0f
#define T1   0.5413248546f   // ln(e-1): softplus(T1) = 1

typedef __bf16 bf16;
typedef _Float16 f16;
typedef __attribute__((ext_vector_type(8))) __bf16 bf16x8;
typedef __attribute__((ext_vector_type(8))) _Float16 f16x8;
typedef __attribute__((ext_vector_type(4))) _Float16 f16x4;
typedef __attribute__((ext_vector_type(2))) _Float16 f16x2;
typedef __attribute__((ext_vector_type(4))) float f32x4;

// fragment-index bases in the packed weight blob (fragment = 64 lanes x 16 B)
#define W3BASE 0         // 9 t3 x 4 kc = 36 tiles -> frags [0, 2304)
#define W1BASE 2304      // 8 tiles               -> frags [2304, 2816)
#define W2BASE 2816      // 8 m-tiles x 4 kc      -> frags [2816, 4864)
#define NFRAG  4864      // 77824 bytes total
#define B3P_OFF (NFRAG * 16)   // byte offset of b3p in d_ws

#define SMEM_BYTES 77824      // 2 blocks/CU (163840/77824 = 2.1)

// One thread per 8-elem A-fragment (W^T in A-layout: A[m=lane&15][k=lq*8+j]).
// k-permutation for W2/W3: feat = (kc*2+(j>>2))*16 + lq*4 + (j&3)  (f mapping,
// matches the in-lane D->B repack of the transposed chain — verified r11/r13).
// W3 COLUMN PERMUTATION (r26): output col' = t3*16+lm in [0,144);
// dim dq = col'/48, j = col'%48; real col = 47*dq + j (j==47 -> zero pad).
__global__ void nsc_prepack(const float* __restrict__ W1, const float* __restrict__ W2,
                            const float* __restrict__ W3, const float* __restrict__ b3,
                            bf16* __restrict__ Wall, float* __restrict__ b3p) {
    int f = blockIdx.x * 256 + threadIdx.x;
    int lane = f & 63, lm = lane & 15, lq = lane >> 4;
    if (f < W1BASE) {                                // W3^T frags (padded cols)
        int tk = f >> 6, t3 = tk >> 2, kc = tk & 3;
        int colp = t3 * 16 + lm;                     // padded col' in [0,144)
        int dq = colp / 48;
        int jj = colp - dq * 48;
        int col = 47 * dq + jj;                      // real col (valid if jj<47)
        bf16x8 pk;
        #pragma unroll
        for (int j = 0; j < 8; ++j) {
            int feat = ((kc * 2 + (j >> 2)) << 4) + (lq << 2) + (j & 3);
            pk[j] = (jj < 47) ? (bf16)W3[feat * OUTD + col] : (bf16)0.f;
        }
        *(bf16x8*)&Wall[(size_t)f * 8] = pk;
    } else if (f < W2BASE) {                         // W1^T frags (identity k, 7 feats)
        int t = (f - W1BASE) >> 6;
        int m = t * 16 + lm;
        bf16x8 pk;
        #pragma unroll
        for (int j = 0; j < 8; ++j) {
            int k = lq * 8 + j;
            pk[j] = (k < 7) ? (bf16)W1[k * HID + m] : (bf16)0.f;
        }
        *(bf16x8*)&Wall[(size_t)f * 8] = pk;
    } else if (f < NFRAG) {                          // W2^T frags
        int tk = (f - W2BASE) >> 6, t2 = tk >> 2, kc = tk & 3;
        int m = t2 * 16 + lm;
        bf16x8 pk;
        #pragma unroll
        for (int j = 0; j < 8; ++j) {
            int feat = ((kc * 2 + (j >> 2)) << 4) + (lq << 2) + (j & 3);
            pk[j] = (bf16)W2[feat * HID + m];
        }
        *(bf16x8*)&Wall[(size_t)f * 8] = pk;
    } else if (f < NFRAG + 144) {                    // b3 permuted+padded to 144
        int i = f - NFRAG;
        int dq = i / 48;
        int jj = i - dq * 48;
        b3p[i] = (jj < 47) ? b3[47 * dq + jj] : 0.f;
    }
}

__global__ __launch_bounds__(NT, 6) void nsc_main(
    const float* __restrict__ x, const float* __restrict__ c,
    const bf16* __restrict__ Wall, const float* __restrict__ b1,
    const float* __restrict__ b2, const float* __restrict__ b3p,
    float* __restrict__ out_y, float* __restrict__ out_ld, int N)
{
    __shared__ __align__(16) char smem[SMEM_BYTES];
    bf16*  wlds  = (bf16*)smem;                 // staged blob (dead after P3)
    f16*   shp16 = (f16*)smem;                  // [256][SRS] OVERLAYS blob after BARRIER A

    const int tid  = threadIdx.x;
    const int g0   = blockIdx.x * TILE;
    const int lane = tid & 63;
    const int wv   = tid >> 6;        // 0..11; waves 0..7 own samples wv*32..+31
    const int lm   = lane & 15;
    const int lq   = lane >> 4;
    const int sbase = wv * 32;

    // ---- Input loads (2 sets/wave, MLP waves only), overlap with staging ----
    float vin[2][8];
    #pragma unroll
    for (int set = 0; set < 2; ++set) {
        #pragma unroll
        for (int j = 0; j < 8; ++j) vin[set][j] = 0.f;
        if (wv < 8) {
            int g = g0 + sbase + set * 16 + lm;
            if (lq == 0 && g < N) {
                vin[set][0] = x[g * 6 + 3]; vin[set][1] = x[g * 6 + 4];
                vin[set][2] = x[g * 6 + 5];
                vin[set][3] = c[g * 4];     vin[set][4] = c[g * 4 + 1];
                vin[set][5] = c[g * 4 + 2]; vin[set][6] = c[g * 4 + 3];
            }
        }
    }

    // ---- Stage the 77824 B blob: 7 x (dwordx4 load + b128 LDS store) ----
    {
        const float4* src = (const float4*)Wall;
        float4* dst = (float4*)smem;
        #pragma unroll
        for (int j = 0; j < 7; ++j) {
            int idx = tid + j * NT;           // 0..5375, guard to 4863
            if (idx < NFRAG) dst[idx] = src[idx];
        }
    }
    __syncthreads();   // staging complete

    // ---- MLP (waves 0..7 only; waves 8..11 skip to BARRIER A) ----
    f16x4 pk[2][9];
    if (wv < 8) {
        // Build B1 input fragments
        bf16x8 inb[2];
        #pragma unroll
        for (int set = 0; set < 2; ++set) {
            bf16x8 t;
            #pragma unroll
            for (int j = 0; j < 8; ++j) t[j] = (bf16)vin[set][j];
            inb[set] = t;
        }

        // Phase 1: h1^T = W1^T @ in^T + b1 (kc-pair loop, shared frags)
        bf16x8 h1B[2][4];
        #pragma unroll
        for (int kc = 0; kc < 4; ++kc) {
            bf16x8 wf0 = *(const bf16x8*)&wlds[(size_t)((W1BASE + (2 * kc) * 64 + lane)) * 8];
            bf16x8 wf1 = *(const bf16x8*)&wlds[(size_t)((W1BASE + (2 * kc + 1) * 64 + lane)) * 8];
            f32x4 b0 = *(const f32x4*)&b1[(2 * kc) * 16 + lq * 4];
            f32x4 b1v = *(const f32x4*)&b1[(2 * kc + 1) * 16 + lq * 4];
            f32x4 a0s0 = __builtin_amdgcn_mfma_f32_16x16x32_bf16(wf0, inb[0], b0, 0, 0, 0);
            f32x4 a0s1 = __builtin_amdgcn_mfma_f32_16x16x32_bf16(wf0, inb[1], b0, 0, 0, 0);
            f32x4 a1s0 = __builtin_amdgcn_mfma_f32_16x16x32_bf16(wf1, inb[0], b1v, 0, 0, 0);
            f32x4 a1s1 = __builtin_amdgcn_mfma_f32_16x16x32_bf16(wf1, inb[1], b1v, 0, 0, 0);
            // repack: slot (kc,j) <- relu(tile(kc*2+(j>>2)).reg[j&3])
            bf16x8 h0, h1;
            #pragma unroll
            for (int j = 0; j < 4; ++j) {
                h0[j]     = (bf16)fmaxf(a0s0[j], 0.f);
                h0[4 + j] = (bf16)fmaxf(a1s0[j], 0.f);
                h1[j]     = (bf16)fmaxf(a0s1[j], 0.f);
                h1[4 + j] = (bf16)fmaxf(a1s1[j], 0.f);
            }
            h1B[0][kc] = h0;
            h1B[1][kc] = h1;
        }

        // Phase 2: h2^T = W2^T @ h1^T + b2 (shared frags, 2 sets)
        bf16x8 h2B[2][4];
        #pragma unroll
        for (int tp = 0; tp < 4; ++tp) {
            f32x4 acc[2][2];
            #pragma unroll
            for (int dt = 0; dt < 2; ++dt) {
                f32x4 bb = *(const f32x4*)&b2[(tp * 2 + dt) * 16 + lq * 4];
                acc[0][dt] = bb; acc[1][dt] = bb;
            }
            #pragma unroll
            for (int kc = 0; kc < 4; ++kc)
                #pragma unroll
                for (int dt = 0; dt < 2; ++dt) {
                    bf16x8 wf = *(const bf16x8*)&wlds[(size_t)((W2BASE + ((tp * 2 + dt) * 4 + kc) * 64 + lane)) * 8];
                    acc[0][dt] = __builtin_amdgcn_mfma_f32_16x16x32_bf16(wf, h1B[0][kc], acc[0][dt], 0, 0, 0);
                    acc[1][dt] = __builtin_amdgcn_mfma_f32_16x16x32_bf16(wf, h1B[1][kc], acc[1][dt], 0, 0, 0);
                }
            #pragma unroll
            for (int set = 0; set < 2; ++set) {
                bf16x8 hb;
                #pragma unroll
                for (int j = 0; j < 8; ++j)
                    hb[j] = (bf16)fmaxf(acc[set][j >> 2][j & 3], 0.f);
                h2B[set][tp] = hb;      // kc-group of next GEMM == tp (f mapping)
            }
        }

        // Phase 3: p^T = W3^T @ h2^T + b3 -> REGISTERS (shared frags)
        #pragma unroll
        for (int t3 = 0; t3 < 9; ++t3) {
            f32x4 acc[2];
            {
                f32x4 bb = *(const f32x4*)&b3p[t3 * 16 + lq * 4];
                acc[0] = bb; acc[1] = bb;
            }
            #pragma unroll
            for (int kc = 0; kc < 4; ++kc) {
                bf16x8 wf = *(const bf16x8*)&wlds[(size_t)((W3BASE + (t3 * 4 + kc) * 64 + lane)) * 8];
                acc[0] = __builtin_amdgcn_mfma_f32_16x16x32_bf16(wf, h2B[0][kc], acc[0], 0, 0, 0);
                acc[1] = __builtin_amdgcn_mfma_f32_16x16x32_bf16(wf, h2B[1][kc], acc[1], 0, 0, 0);
            }
            #pragma unroll
            for (int set = 0; set < 2; ++set)
                pk[set][t3] = (f16x4){(f16)acc[set][0], (f16)acc[set][1],
                                      (f16)acc[set][2], (f16)acc[set][3]};
        }
    }
    __syncthreads();   // BARRIER A: ALL blob reads done -> shp16 may overlay

    // ---- Scatter p registers to shp16 (UNIFORM: padded layout) ----
    if (wv < 8) {
        #pragma unroll
        for (int set = 0; set < 2; ++set) {
            int s = sbase + set * 16 + lm;
            #pragma unroll
            for (int t3 = 0; t3 < 9; ++t3)
                *(f16x4*)&shp16[s * SRS + t3 * 16 + lq * 4] = pk[set][t3];
        }
    }
    __syncthreads();   // BARRIER B: scatters visible to all waves

    // ---- Phase 4: spline; 12 groups / 12 waves — ONE body per wave ----
    {
        const int grp = wv;
        const int d = grp >> 2;
        const int s = (grp & 3) * 64 + lane;
        const int g = g0 + s;
        if (g < N) {
            // ONE branchless gather: dim d at halves 48*d (16B aligned)
            const f16* pr = &shp16[s * SRS + 48 * d];
            float w_[16], h_[16], dl[15];
            {
                f16x8 A0 = *(const f16x8*)&pr[0],  A1 = *(const f16x8*)&pr[8];
                f16x8 A2 = *(const f16x8*)&pr[16], A3 = *(const f16x8*)&pr[24];
                f16x8 A4 = *(const f16x8*)&pr[32], A5 = *(const f16x8*)&pr[40];
                #pragma unroll
                for (int i = 0; i < 8; ++i) {
                    w_[i] = (float)A0[i]; w_[8 + i] = (float)A1[i];
                    h_[i] = (float)A2[i]; h_[8 + i] = (float)A3[i];
                    dl[i] = (float)A4[i];
                }
                #pragma unroll
                for (int i = 0; i < 7; ++i) dl[8 + i] = (float)A5[i];
            }

            // exp (UNNORMALIZED; logits are O(1), no max-subtract needed)
            float sw = 0.f, sh = 0.f;
            #pragma unroll
            for (int i = 0; i < 16; ++i) { w_[i] = __expf(w_[i]); sw += w_[i]; }
            #pragma unroll
            for (int i = 0; i < 16; ++i) { h_[i] = __expf(h_[i]); sh += h_[i]; }
            float cwn = 10.f * __builtin_amdgcn_rcpf(sw);
            float chn = 10.f * __builtin_amdgcn_rcpf(sh);

            float xv = x[g * 6 + d];
            bool oob = (xv <= -BND) || (xv >= BND);
            float xm = oob ? -BND : xv;

            // DEFERRED-NORM bin scan: xm >= -B + cwn*prefix  <=>  txm >= prefix
            float txm = (xm + BND) * sw * 0.1f;
            float cum_u = w_[0], cumy_u = h_[0];
            float px_u = 0.f, py_u = 0.f;
            float wk_u = w_[0], hk_u = h_[0];
            float d0l = T1, d1l = dl[0];
            #pragma unroll
            for (int i = 1; i < 16; ++i) {
                bool ge = (txm >= cum_u);
                if (ge) {
                    px_u = cum_u; py_u = cumy_u;
                    wk_u = w_[i]; hk_u = h_[i];
                    d0l = dl[i - 1];
                    d1l = (i < 15) ? dl[i] : T1;
                }
                cum_u += w_[i]; cumy_u += h_[i];
            }
            // normalize only the selected values
            float xk_b = -BND + cwn * px_u;
            float yk_b = -BND + chn * py_u;
            float wk = cwn * wk_u;
            float hk = chn * hk_u;

            float d0 = (d0l > 15.f) ? d0l : __logf(1.f + __expf(d0l));
            float d1 = (d1l > 15.f) ? d1l : __logf(1.f + __expf(d1l));

            float rwk = __builtin_amdgcn_rcpf(wk);
            float sk = hk * rwk;
            float relx = (xm - xk_b) * rwk;
            relx = fminf(fmaxf(relx, 0.f), 1.f);
            float r1 = relx * (1.f - relx);
            float den = sk + (d1 + d0 - 2.f * sk) * r1;
            float iden = __builtin_amdgcn_rcpf(den);
            float num = hk * (sk * relx * relx + d0 * r1);
            float y = yk_b + num * iden;
            float omr = 1.f - relx;
            float arg = d1 * relx * relx + 2.f * sk * r1 + d0 * omr * omr;
            float ratio = sk * iden;
            float ld = __logf(ratio * ratio * arg);   // 2log(sk)+log(arg)-2log(den)
            if (oob) { y = xv; ld = 0.f; }

            out_y[g * 6 + d] = y;
            out_y[g * 6 + 3 + d] = x[g * 6 + 3 + d];  // upper pass-through (fp32)
            // ld into row pad (halves 144..149; readers only touch 0..143)
            float* lp = (float*)&shp16[s * SRS + 144];
            lp[d] = ld;
        }
    }
    __syncthreads();   // BARRIER C

    // ---- Phase 5: reduce log-det over the 3 dims (from row pads) ----
    if (tid < TILE) {
        int g = g0 + tid;
        if (g < N) {
            const float* lp = (const float*)&shp16[tid * SRS + 144];
            out_ld[g] = lp[0] + lp[1] + lp[2];
        }
    }
}

extern "C" void kernel_launch(void* const* d_in, const int* in_sizes, int n_in,
                              void* d_out, int out_size, void* d_ws, size_t ws_size,
                              hipStream_t stream) {
    const float* x  = (const float*)d_in[0];
    const float* c  = (const float*)d_in[1];
    const float* W1 = (const float*)d_in[2];
    const float* b1 = (const float*)d_in[3];
    const float* W2 = (const float*)d_in[4];
    const float* b2 = (const float*)d_in[5];
    const float* W3 = (const float*)d_in[6];
    const float* b3 = (const float*)d_in[7];

    const int N = in_sizes[0] / 6;              // 500000
    float* out_y  = (float*)d_out;
    float* out_ld = (float*)d_out + (size_t)N * 6;

    bf16*  Wall = (bf16*)d_ws;                          // 77824 B blob
    float* b3p  = (float*)((char*)d_ws + B3P_OFF);      // 576 B (144 floats)

    int nthreads = NFRAG + 144;                 // 5008
    nsc_prepack<<<(nthreads + 255) / 256, 256, 0, stream>>>(W1, W2, W3, b3,
                                                            Wall, b3p);

    int nblocks = (N + TILE - 1) / TILE;        // 1954
    nsc_main<<<nblocks, NT, 0, stream>>>(x, c, Wall, b1, b2, b3p,
                                         out_y, out_ld, N);
}